// Round 3
// baseline (513.538 us; speedup 1.0000x reference)
//
#include <hip/hip_runtime.h>

// Problem constants
#define N_NODES 4096
#define C_IN    256
#define HID     256
#define BATCH   8
#define R_TOT   32768   // BATCH * N_NODES

typedef unsigned short u16;
typedef short s8v  __attribute__((ext_vector_type(8)));   // 8 bf16 (bit pattern in shorts)
typedef float f4v  __attribute__((ext_vector_type(4)));
typedef u16   u16x4 __attribute__((ext_vector_type(4)));

#define MFMA(a,b,c) __builtin_amdgcn_mfma_f32_16x16x32_bf16((a),(b),(c),0,0,0)

__device__ __forceinline__ u16 bf_rne(float x) {
    unsigned u = __float_as_uint(x);
    u += 0x7fffu + ((u >> 16) & 1u);
    return (u16)(u >> 16);
}
__device__ __forceinline__ float bf_f(u16 h) {
    return __uint_as_float(((unsigned)h) << 16);
}
// fp32 -> bf16 hi/lo split: x ~= hi + lo, |err| <= 2^-18 |x|
__device__ __forceinline__ void split2f(float x, u16& h, u16& l) {
    h = bf_rne(x);
    l = bf_rne(x - bf_f(h));
}

// async global->LDS, 16B per lane. lds ptr must be wave-uniform (dest = base + lane*16)
__device__ __forceinline__ void glds16(const void* g, void* l) {
    __builtin_amdgcn_global_load_lds(
        (const __attribute__((address_space(1))) void*)g,
        (__attribute__((address_space(3))) void*)l, 16, 0, 0);
}

// ---------------- split kernels ----------------

// elementwise fp32 -> (hi,lo) bf16, float4-vectorized
__global__ void splitK_k(const float* __restrict__ in, u16* __restrict__ oh,
                         u16* __restrict__ ol, int n4) {
    int i = blockIdx.x * blockDim.x + threadIdx.x;
    int stride = gridDim.x * blockDim.x;
    for (; i < n4; i += stride) {
        float4 x = ((const float4*)in)[i];
        u16x4 hh, ll; u16 a, b;
        split2f(x.x, a, b); hh[0] = a; ll[0] = b;
        split2f(x.y, a, b); hh[1] = a; ll[1] = b;
        split2f(x.z, a, b); hh[2] = a; ll[2] = b;
        split2f(x.w, a, b); hh[3] = a; ll[3] = b;
        ((u16x4*)oh)[i] = hh; ((u16x4*)ol)[i] = ll;
    }
}

// transpose + split for the 256x256 weight matrices: out[h][c] = in[c][h]
__global__ void splitT_k(const float* __restrict__ in, u16* __restrict__ oh,
                         u16* __restrict__ ol) {
    int c = blockIdx.x;      // row of in
    int h = threadIdx.x;     // col of in
    float v = in[c * 256 + h];
    u16 hi, lo; split2f(v, hi, lo);
    oh[h * 256 + c] = hi;
    ol[h * 256 + c] = lo;
}

// ---------------- small GEMM: T[i=hid'][j=r] = sum_k Wt[i][k] * Bf[j][k] + bias[i] ----------------
// A (Wt) pre-split bf16 [256][256]; B fp32 [32768][256] reg-staged+split on the fly.
// Output written split hi/lo, transposed layout [256][32768]. No relu.
__global__ __launch_bounds__(256, 2) void gemm_small_k(
    const u16* __restrict__ Ah, const u16* __restrict__ Al,
    const float* __restrict__ Bf, const float* __restrict__ bias,
    u16* __restrict__ Oh, u16* __restrict__ Ol)
{
    __shared__ u16 sAh[4096], sAl[4096], sBh[4096], sBl[4096];  // 128x32 each
    const int tid = threadIdx.x;
    const int w = tid >> 6, lane = tid & 63;
    const int i0 = blockIdx.x * 128;   // output row tile (hid')
    const int r0 = blockIdx.y * 128;   // output col tile (r)
    const int lr = lane & 15, lk = lane >> 4;
    const int wr = (w >> 1) * 64, wc = (w & 1) * 64;
    const int kslot = (lk ^ ((lr >> 1) & 3)) * 8;   // swizzled read slot (u16 units)

    const u16 *pAh[2], *pAl[2];
    const int cb = ((lane & 3) ^ ((lane >> 3) & 3)) * 8;  // pre-swizzled source slot
#pragma unroll
    for (int j = 0; j < 2; ++j) {
        const int ra = i0 + (w * 2 + j) * 16 + (lane >> 2);
        pAh[j] = Ah + (size_t)ra * 256 + cb;
        pAl[j] = Al + (size_t)ra * 256 + cb;
    }

    f4v acc[4][4] = {};

    for (int kt = 0; kt < 8; ++kt) {
        // stage A hi/lo via global_load_lds (linear 1KB chunks, source pre-swizzled)
#pragma unroll
        for (int j = 0; j < 2; ++j) {
            glds16(pAh[j] + kt * 32, sAh + (w * 2 + j) * 512);
            glds16(pAl[j] + kt * 32, sAl + (w * 2 + j) * 512);
        }
        // stage B: load fp32, split to hi/lo, ds_write at swizzled slot
#pragma unroll
        for (int i = 0; i < 4; ++i) {
            const int cc  = tid + i * 256;
            const int row = cc >> 3;
            const int col = (((((cc & 7) >> 1) ^ ((cc >> 4) & 3)) << 3)) | ((cc & 1) * 4);
            const float* src = Bf + (size_t)(r0 + row) * 256 + kt * 32 + (cc & 7) * 4;
            float4 x = *(const float4*)src;
            u16x4 hh, ll; u16 a, b;
            split2f(x.x, a, b); hh[0] = a; ll[0] = b;
            split2f(x.y, a, b); hh[1] = a; ll[1] = b;
            split2f(x.z, a, b); hh[2] = a; ll[2] = b;
            split2f(x.w, a, b); hh[3] = a; ll[3] = b;
            *(u16x4*)(sBh + row * 32 + col) = hh;
            *(u16x4*)(sBl + row * 32 + col) = ll;
        }
        __syncthreads();

        s8v fah[4], fal[4], fbh[4], fbl[4];
#pragma unroll
        for (int m = 0; m < 4; ++m) {
            fah[m] = *(const s8v*)(sAh + (wr + m * 16 + lr) * 32 + kslot);
            fal[m] = *(const s8v*)(sAl + (wr + m * 16 + lr) * 32 + kslot);
            fbh[m] = *(const s8v*)(sBh + (wc + m * 16 + lr) * 32 + kslot);
            fbl[m] = *(const s8v*)(sBl + (wc + m * 16 + lr) * 32 + kslot);
        }
#pragma unroll
        for (int m = 0; m < 4; ++m)
#pragma unroll
            for (int n = 0; n < 4; ++n)
                acc[m][n] = MFMA(fah[m], fbh[n], acc[m][n]);
#pragma unroll
        for (int m = 0; m < 4; ++m)
#pragma unroll
            for (int n = 0; n < 4; ++n)
                acc[m][n] = MFMA(fah[m], fbl[n], acc[m][n]);
#pragma unroll
        for (int m = 0; m < 4; ++m)
#pragma unroll
            for (int n = 0; n < 4; ++n)
                acc[m][n] = MFMA(fal[m], fbh[n], acc[m][n]);
        __syncthreads();
    }

    // epilogue: +bias, split, store transposed output [hid'][32768]
#pragma unroll
    for (int m = 0; m < 4; ++m) {
#pragma unroll
        for (int q = 0; q < 4; ++q) {
            const int rowg = i0 + wr + m * 16 + lk * 4 + q;
            const float bv = bias[rowg];
#pragma unroll
            for (int n = 0; n < 4; ++n) {
                const int colg = r0 + wc + n * 16 + lr;
                float v = acc[m][n][q] + bv;
                u16 hi, lo; split2f(v, hi, lo);
                const size_t off = (size_t)rowg * R_TOT + colg;
                Oh[off] = hi; Ol[off] = lo;
            }
        }
    }
}

// ---------------- big GEMM: H[b][i=n][j=h] = relu( sum_m G[i][m] * Tt[j][b*4096+m] ) ----------------
// A = G pre-split [4096][4096]; B = Tt pre-split [256][32768]. Output fp32 [32768][256].
// Depth-2 prefetch, raw s_barrier + counted vmcnt (T3+T4), setprio around MFMA (T5),
// swizzled LDS tiles (T2). 2 blocks/CU.
__global__ __launch_bounds__(256, 2) void gemm_big_k(
    const u16* __restrict__ Gh, const u16* __restrict__ Gl,
    const u16* __restrict__ Th, const u16* __restrict__ Tl,
    float* __restrict__ Hout)
{
    __shared__ u16 lds[2][4][4096];   // [buf][Ah,Al,Bh,Bl][128x32], 64 KB
    const int tid = threadIdx.x;
    const int w = tid >> 6, lane = tid & 63;
    const int n0 = blockIdx.x * 128;
    const int h0 = blockIdx.y * 128;
    const int b  = blockIdx.z;
    const int lr = lane & 15, lk = lane >> 4;
    const int wr = (w >> 1) * 64, wc = (w & 1) * 64;
    const int kslot = (lk ^ ((lr >> 1) & 3)) * 8;   // swizzled read slot (u16 units)

    const u16 *pAh[2], *pAl[2], *pBh[2], *pBl[2];
    const int cb = ((lane & 3) ^ ((lane >> 3) & 3)) * 8;  // pre-swizzled source slot
#pragma unroll
    for (int j = 0; j < 2; ++j) {
        const int ra = n0 + (w * 2 + j) * 16 + (lane >> 2);
        pAh[j] = Gh + (size_t)ra * 4096 + cb;
        pAl[j] = Gl + (size_t)ra * 4096 + cb;
        const int rb = h0 + (w * 2 + j) * 16 + (lane >> 2);
        pBh[j] = Th + (size_t)rb * R_TOT + (size_t)b * 4096 + cb;
        pBl[j] = Tl + (size_t)rb * R_TOT + (size_t)b * 4096 + cb;
    }

    f4v acc[4][4] = {};

// issue 8 global_load_lds for the next-unstaged K-tile into buffer BUF, advance ptrs
#define STAGE(BUF) do {                                                        \
    _Pragma("unroll")                                                          \
    for (int j = 0; j < 2; ++j) {                                              \
        glds16(pAh[j], &lds[BUF][0][(w * 2 + j) * 512]);                       \
        glds16(pAl[j], &lds[BUF][1][(w * 2 + j) * 512]);                       \
        glds16(pBh[j], &lds[BUF][2][(w * 2 + j) * 512]);                       \
        glds16(pBl[j], &lds[BUF][3][(w * 2 + j) * 512]);                       \
    }                                                                          \
    _Pragma("unroll")                                                          \
    for (int j = 0; j < 2; ++j) {                                              \
        pAh[j] += 32; pAl[j] += 32; pBh[j] += 32; pBl[j] += 32;                \
    }                                                                          \
} while (0)

#define COMPUTE(BUF) do {                                                      \
    s8v fah[4], fal[4], fbh[4], fbl[4];                                        \
    _Pragma("unroll")                                                          \
    for (int m = 0; m < 4; ++m) {                                              \
        fah[m] = *(const s8v*)(&lds[BUF][0][(wr + m * 16 + lr) * 32 + kslot]); \
        fal[m] = *(const s8v*)(&lds[BUF][1][(wr + m * 16 + lr) * 32 + kslot]); \
        fbh[m] = *(const s8v*)(&lds[BUF][2][(wc + m * 16 + lr) * 32 + kslot]); \
        fbl[m] = *(const s8v*)(&lds[BUF][3][(wc + m * 16 + lr) * 32 + kslot]); \
    }                                                                          \
    __builtin_amdgcn_s_setprio(1);                                             \
    _Pragma("unroll")                                                          \
    for (int m = 0; m < 4; ++m)                                                \
        _Pragma("unroll")                                                      \
        for (int n = 0; n < 4; ++n)                                            \
            acc[m][n] = MFMA(fah[m], fbh[n], acc[m][n]);                       \
    _Pragma("unroll")                                                          \
    for (int m = 0; m < 4; ++m)                                                \
        _Pragma("unroll")                                                      \
        for (int n = 0; n < 4; ++n)                                            \
            acc[m][n] = MFMA(fah[m], fbl[n], acc[m][n]);                       \
    _Pragma("unroll")                                                          \
    for (int m = 0; m < 4; ++m)                                                \
        _Pragma("unroll")                                                      \
        for (int n = 0; n < 4; ++n)                                            \
            acc[m][n] = MFMA(fal[m], fbh[n], acc[m][n]);                       \
    __builtin_amdgcn_s_setprio(0);                                             \
} while (0)

#define VMCNT8()  asm volatile("s_waitcnt vmcnt(8)" ::: "memory")
#define VMCNT0()  asm volatile("s_waitcnt vmcnt(0)" ::: "memory")
#define BAR()     __builtin_amdgcn_s_barrier()
#define SCHEDBAR() __builtin_amdgcn_sched_barrier(0)

    // prologue: stage tiles t0 (buf0) and t1 (buf1); 16 loads in flight
    STAGE(0);
    STAGE(1);

    // steady state t = 0..125: 2 barriers/step, counted vmcnt, stage t+2
    for (int t = 0; t < 126; t += 2) {
        VMCNT8();            // my tile-t loads landed (t+1's 8 stay in flight)
        BAR();               // all waves' tile-t loads landed
        COMPUTE(0);
        SCHEDBAR();          // pin ds_reads above the barrier (no race with STAGE)
        BAR();               // everyone done reading buf0
        STAGE(0);            // stage tile t+2
        VMCNT8();
        BAR();
        COMPUTE(1);
        SCHEDBAR();
        BAR();
        STAGE(1);            // stage tile t+3
    }
    // epilogue: t=126 (buf0), t=127 (buf1) — nothing left to stage
    VMCNT8();
    BAR();
    COMPUTE(0);
    SCHEDBAR();
    BAR();
    VMCNT0();
    BAR();
    COMPUTE(1);

#undef STAGE
#undef COMPUTE
#undef VMCNT8
#undef VMCNT0
#undef BAR
#undef SCHEDBAR

    // epilogue: relu, store fp32 H[b*4096+row][col]
    float* out = Hout + ((size_t)b * 4096 + n0 + wr + lk * 4) * 256 + h0 + wc + lr;
#pragma unroll
    for (int m = 0; m < 4; ++m)
#pragma unroll
        for (int n = 0; n < 4; ++n)
#pragma unroll
            for (int q = 0; q < 4; ++q) {
                float v = acc[m][n][q];
                v = v > 0.f ? v : 0.f;
                out[(size_t)(m * 16 + q) * 256 + n * 16] = v;
            }
}

// ---------------- final MLP: out[r] = relu(H[r,:] @ Wm1 + bm1) @ Wm2 + bm2 ----------------
__global__ __launch_bounds__(256) void mlp_k(
    const float* __restrict__ H, const float* __restrict__ Wm1,
    const float* __restrict__ bm1, const float* __restrict__ Wm2,
    const float* __restrict__ bm2, float* __restrict__ out)
{
    __shared__ float rb[4][256];
    const int w = threadIdx.x >> 6, lane = threadIdx.x & 63;
    const int gw0 = blockIdx.x * 4 + w;
    const int stride = gridDim.x * 4;
    for (int r = gw0; r < R_TOT; r += stride) {
        float4 v = *(const float4*)(H + (size_t)r * 256 + lane * 4);
        *(float4*)&rb[w][lane * 4] = v;
        __syncthreads();
        float acc = 0.f;
#pragma unroll 8
        for (int k = 0; k < 256; ++k)
            acc = fmaf(rb[w][k], Wm1[k * 64 + lane], acc);
        float m = acc + bm1[lane];
        m = m > 0.f ? m : 0.f;
        float s = m * Wm2[lane];
#pragma unroll
        for (int off = 32; off; off >>= 1) s += __shfl_down(s, off);
        if (lane == 0) out[r] = s + bm2[0];
        __syncthreads();
    }
}

// ---------------- launch ----------------
extern "C" void kernel_launch(void* const* d_in, const int* in_sizes, int n_in,
                              void* d_out, int out_size, void* d_ws, size_t ws_size,
                              hipStream_t stream) {
    (void)in_sizes; (void)n_in; (void)out_size; (void)ws_size;
    const float* X   = (const float*)d_in[0];
    const float* G   = (const float*)d_in[1];
    const float* W1  = (const float*)d_in[2];
    const float* b1  = (const float*)d_in[3];
    const float* W2  = (const float*)d_in[4];
    const float* b2  = (const float*)d_in[5];
    const float* Wm1 = (const float*)d_in[6];
    const float* bm1 = (const float*)d_in[7];
    const float* Wm2 = (const float*)d_in[8];
    const float* bm2 = (const float*)d_in[9];
    float* out = (float*)d_out;

    char* ws = (char*)d_ws;
    u16* Gh   = (u16*)(ws);                     // 33554432 B
    u16* Gl   = (u16*)(ws + 33554432u);         // 33554432 B
    u16* W1th = (u16*)(ws + 67108864u);         // 131072 B
    u16* W1tl = (u16*)(ws + 67239936u);
    u16* W2th = (u16*)(ws + 67371008u);
    u16* W2tl = (u16*)(ws + 67502080u);
    u16* Tth  = (u16*)(ws + 67633152u);         // 16777216 B
    u16* Ttl  = (u16*)(ws + 84410368u);         // 16777216 B
    float* Hb = (float*)(ws + 101187584u);      // 33554432 B  (total 134742016 B)

    splitK_k<<<2048, 256, 0, stream>>>(G, Gh, Gl, 16777216 / 4);
    splitT_k<<<256, 256, 0, stream>>>(W1, W1th, W1tl);
    splitT_k<<<256, 256, 0, stream>>>(W2, W2th, W2tl);

    // conv1 pre-prop: T1t = (X @ W1 + b1)^T, split
    gemm_small_k<<<dim3(2, 256), 256, 0, stream>>>(W1th, W1tl, X, b1, Tth, Ttl);
    // conv1 prop: H1 = relu(G @ T1)
    gemm_big_k<<<dim3(32, 2, 8), 256, 0, stream>>>(Gh, Gl, Tth, Ttl, Hb);
    // conv2 pre-prop: T2t = (H1 @ W2 + b2)^T, split
    gemm_small_k<<<dim3(2, 256), 256, 0, stream>>>(W2th, W2tl, Hb, b2, Tth, Ttl);
    // conv2 prop: H2 = relu(G @ T2)
    gemm_big_k<<<dim3(32, 2, 8), 256, 0, stream>>>(Gh, Gl, Tth, Ttl, Hb);
    // final MLP
    mlp_k<<<2048, 256, 0, stream>>>(Hb, Wm1, bm1, Wm2, bm2, out);
}

// Round 4
// 450.576 us; speedup vs baseline: 1.1397x; 1.1397x over previous
//
#include <hip/hip_runtime.h>

// Problem constants
#define N_NODES 4096
#define C_IN    256
#define HID     256
#define BATCH   8
#define R_TOT   32768   // BATCH * N_NODES

typedef unsigned short u16;
typedef short s8v  __attribute__((ext_vector_type(8)));   // 8 bf16 (bit pattern in shorts)
typedef float f4v  __attribute__((ext_vector_type(4)));
typedef u16   u16x4 __attribute__((ext_vector_type(4)));

#define MFMA(a,b,c) __builtin_amdgcn_mfma_f32_16x16x32_bf16((a),(b),(c),0,0,0)

__device__ __forceinline__ u16 bf_rne(float x) {
    unsigned u = __float_as_uint(x);
    u += 0x7fffu + ((u >> 16) & 1u);
    return (u16)(u >> 16);
}
__device__ __forceinline__ float bf_f(u16 h) {
    return __uint_as_float(((unsigned)h) << 16);
}
// fp32 -> bf16 hi/lo split: x ~= hi + lo, |err| <= 2^-18 |x|
__device__ __forceinline__ void split2f(float x, u16& h, u16& l) {
    h = bf_rne(x);
    l = bf_rne(x - bf_f(h));
}

// async global->LDS, 16B per lane. lds ptr must be wave-uniform (dest = base + lane*16)
__device__ __forceinline__ void glds16(const void* g, void* l) {
    __builtin_amdgcn_global_load_lds(
        (const __attribute__((address_space(1))) void*)g,
        (__attribute__((address_space(3))) void*)l, 16, 0, 0);
}

// ---------------- split kernels ----------------

__global__ void splitK_k(const float* __restrict__ in, u16* __restrict__ oh,
                         u16* __restrict__ ol, int n4) {
    int i = blockIdx.x * blockDim.x + threadIdx.x;
    int stride = gridDim.x * blockDim.x;
    for (; i < n4; i += stride) {
        float4 x = ((const float4*)in)[i];
        u16x4 hh, ll; u16 a, b;
        split2f(x.x, a, b); hh[0] = a; ll[0] = b;
        split2f(x.y, a, b); hh[1] = a; ll[1] = b;
        split2f(x.z, a, b); hh[2] = a; ll[2] = b;
        split2f(x.w, a, b); hh[3] = a; ll[3] = b;
        ((u16x4*)oh)[i] = hh; ((u16x4*)ol)[i] = ll;
    }
}

// transpose + split for the 256x256 weight matrices: out[h][c] = in[c][h]
__global__ void splitT_k(const float* __restrict__ in, u16* __restrict__ oh,
                         u16* __restrict__ ol) {
    int c = blockIdx.x;      // row of in
    int h = threadIdx.x;     // col of in
    float v = in[c * 256 + h];
    u16 hi, lo; split2f(v, hi, lo);
    oh[h * 256 + c] = hi;
    ol[h * 256 + c] = lo;
}

// ---------------- small GEMM (unchanged, proven): T[i=hid'][j=r] ----------------
__global__ __launch_bounds__(256, 2) void gemm_small_k(
    const u16* __restrict__ Ah, const u16* __restrict__ Al,
    const float* __restrict__ Bf, const float* __restrict__ bias,
    u16* __restrict__ Oh, u16* __restrict__ Ol)
{
    __shared__ u16 sAh[4096], sAl[4096], sBh[4096], sBl[4096];  // 128x32 each
    const int tid = threadIdx.x;
    const int w = tid >> 6, lane = tid & 63;
    const int i0 = blockIdx.x * 128;   // output row tile (hid')
    const int r0 = blockIdx.y * 128;   // output col tile (r)
    const int lr = lane & 15, lk = lane >> 4;
    const int wr = (w >> 1) * 64, wc = (w & 1) * 64;
    const int kslot = (lk ^ ((lr >> 1) & 3)) * 8;   // swizzled read slot (u16 units)

    const u16 *pAh[2], *pAl[2];
    const int cb = ((lane & 3) ^ ((lane >> 3) & 3)) * 8;  // pre-swizzled source slot
#pragma unroll
    for (int j = 0; j < 2; ++j) {
        const int ra = i0 + (w * 2 + j) * 16 + (lane >> 2);
        pAh[j] = Ah + (size_t)ra * 256 + cb;
        pAl[j] = Al + (size_t)ra * 256 + cb;
    }

    f4v acc[4][4] = {};

    for (int kt = 0; kt < 8; ++kt) {
#pragma unroll
        for (int j = 0; j < 2; ++j) {
            glds16(pAh[j] + kt * 32, sAh + (w * 2 + j) * 512);
            glds16(pAl[j] + kt * 32, sAl + (w * 2 + j) * 512);
        }
#pragma unroll
        for (int i = 0; i < 4; ++i) {
            const int cc  = tid + i * 256;
            const int row = cc >> 3;
            const int col = (((((cc & 7) >> 1) ^ ((cc >> 4) & 3)) << 3)) | ((cc & 1) * 4);
            const float* src = Bf + (size_t)(r0 + row) * 256 + kt * 32 + (cc & 7) * 4;
            float4 x = *(const float4*)src;
            u16x4 hh, ll; u16 a, b;
            split2f(x.x, a, b); hh[0] = a; ll[0] = b;
            split2f(x.y, a, b); hh[1] = a; ll[1] = b;
            split2f(x.z, a, b); hh[2] = a; ll[2] = b;
            split2f(x.w, a, b); hh[3] = a; ll[3] = b;
            *(u16x4*)(sBh + row * 32 + col) = hh;
            *(u16x4*)(sBl + row * 32 + col) = ll;
        }
        __syncthreads();

        s8v fah[4], fal[4], fbh[4], fbl[4];
#pragma unroll
        for (int m = 0; m < 4; ++m) {
            fah[m] = *(const s8v*)(sAh + (wr + m * 16 + lr) * 32 + kslot);
            fal[m] = *(const s8v*)(sAl + (wr + m * 16 + lr) * 32 + kslot);
            fbh[m] = *(const s8v*)(sBh + (wc + m * 16 + lr) * 32 + kslot);
            fbl[m] = *(const s8v*)(sBl + (wc + m * 16 + lr) * 32 + kslot);
        }
#pragma unroll
        for (int m = 0; m < 4; ++m)
#pragma unroll
            for (int n = 0; n < 4; ++n)
                acc[m][n] = MFMA(fah[m], fbh[n], acc[m][n]);
#pragma unroll
        for (int m = 0; m < 4; ++m)
#pragma unroll
            for (int n = 0; n < 4; ++n)
                acc[m][n] = MFMA(fah[m], fbl[n], acc[m][n]);
#pragma unroll
        for (int m = 0; m < 4; ++m)
#pragma unroll
            for (int n = 0; n < 4; ++n)
                acc[m][n] = MFMA(fal[m], fbh[n], acc[m][n]);
        __syncthreads();
    }

#pragma unroll
    for (int m = 0; m < 4; ++m) {
#pragma unroll
        for (int q = 0; q < 4; ++q) {
            const int rowg = i0 + wr + m * 16 + lk * 4 + q;
            const float bv = bias[rowg];
#pragma unroll
            for (int n = 0; n < 4; ++n) {
                const int colg = r0 + wc + n * 16 + lr;
                float v = acc[m][n][q] + bv;
                u16 hi, lo; split2f(v, hi, lo);
                const size_t off = (size_t)rowg * R_TOT + colg;
                Oh[off] = hi; Ol[off] = lo;
            }
        }
    }
}

// ---------------- big GEMM: H[b][i=n][j=h] = relu( sum_m G[i][m] * Tt[j][b*4096+m] ) ----------------
// 8-phase-style schedule: BM=256 BN=128 BK=32, 8 waves (4Mx2N, per-wave 64x64),
// triple-buffered LDS (3 x 48KB, dynamic), 4 phases/K-tile, counted vmcnt(6) once
// per tile, setprio around MFMA clusters. Swizzled tiles (pre-swizzled source).
// Buffer layout (u16): [A-hi 256x32 | A-lo 256x32 | B-hi 128x32 | B-lo 128x32] = 24576 u16.
__global__ __launch_bounds__(512, 2) void gemm_big_k(
    const u16* __restrict__ Gh, const u16* __restrict__ Gl,
    const u16* __restrict__ Th, const u16* __restrict__ Tl,
    float* __restrict__ Hout)
{
    extern __shared__ u16 lds[];   // 3 * 24576 u16 = 147456 B
    const int tid = threadIdx.x;
    const int w = tid >> 6, l = tid & 63;
    const int n0 = blockIdx.x * 256;
    const int h0 = blockIdx.y * 128;
    const int b  = blockIdx.z;
    const int lr = l & 15, lk = l >> 4;
    const int kslot8 = (lk ^ ((lr >> 1) & 3)) * 8;  // swizzled read slot (u16)
    const int wm = w >> 1, wn = w & 1;

    const int cb = ((l & 3) ^ ((l >> 3) & 3)) * 8;  // pre-swizzled source slot
    const u16* pAh0 = Gh + (size_t)(n0 + 16 * w + (l >> 2)) * 4096 + cb;
    const u16* pAh1 = pAh0 + 128 * 4096;
    const u16* pAl0 = Gl + (size_t)(n0 + 16 * w + (l >> 2)) * 4096 + cb;
    const u16* pAl1 = pAl0 + 128 * 4096;
    const u16* pBh  = Th + (size_t)(h0 + (tid >> 2)) * R_TOT + (size_t)b * 4096 + cb;
    const u16* pBl  = Tl + (size_t)(h0 + (tid >> 2)) * R_TOT + (size_t)b * 4096 + cb;

    // wave-uniform LDS stage bases (u16 units)
    const int aw0 = (16 * w) * 32;           // A j=0; j=1 adds 4096
    const int bw  = 16384 + (16 * w) * 32;   // B-hi; B-lo adds 4096

    f4v acc[4][4] = {};

#define STAGE6(STG) do {                                                       \
    u16* Ls = lds + (STG) * 24576;                                             \
    glds16(pAh0, Ls + aw0);                                                    \
    glds16(pAh1, Ls + aw0 + 4096);                                             \
    glds16(pAl0, Ls + 8192 + aw0);                                             \
    glds16(pAl1, Ls + 8192 + aw0 + 4096);                                      \
    glds16(pBh,  Ls + bw);                                                     \
    glds16(pBl,  Ls + bw + 4096);                                              \
    pAh0 += 32; pAh1 += 32; pAl0 += 32; pAl1 += 32; pBh += 32; pBl += 32;      \
} while (0)

// One K-tile: 4 phases. VMODE: 0 = vmcnt(6) (steady), 1 = vmcnt(0) (drain), 2 = skip.
#define KTILE(CUR, STG, DO_STAGE, VMODE) do {                                  \
    const u16* Lc = lds + (CUR) * 24576;                                       \
    u16* Ls = lds + (STG) * 24576;                                             \
    s8v fah[4], fal[4], fbh[4], fbl[4];                                        \
    /* P0: read A-hi + B-hi, stage A-hi pair */                                \
    _Pragma("unroll") for (int m = 0; m < 4; ++m)                              \
        fah[m] = *(const s8v*)(Lc + (wm * 64 + m * 16 + lr) * 32 + kslot8);    \
    _Pragma("unroll") for (int n = 0; n < 4; ++n)                              \
        fbh[n] = *(const s8v*)(Lc + 16384 + (wn * 64 + n * 16 + lr) * 32 + kslot8); \
    if (DO_STAGE) { glds16(pAh0, Ls + aw0); glds16(pAh1, Ls + aw0 + 4096); }   \
    __builtin_amdgcn_s_barrier();                                              \
    __builtin_amdgcn_s_setprio(1);                                             \
    _Pragma("unroll") for (int m = 0; m < 2; ++m)                              \
        _Pragma("unroll") for (int n = 0; n < 4; ++n)                          \
            acc[m][n] = MFMA(fah[m], fbh[n], acc[m][n]);                       \
    __builtin_amdgcn_s_setprio(0);                                             \
    __builtin_amdgcn_s_barrier();                                              \
    /* P1: read B-lo, stage A-lo pair */                                       \
    _Pragma("unroll") for (int n = 0; n < 4; ++n)                              \
        fbl[n] = *(const s8v*)(Lc + 20480 + (wn * 64 + n * 16 + lr) * 32 + kslot8); \
    if (DO_STAGE) { glds16(pAl0, Ls + 8192 + aw0); glds16(pAl1, Ls + 8192 + aw0 + 4096); } \
    __builtin_amdgcn_s_barrier();                                              \
    __builtin_amdgcn_s_setprio(1);                                             \
    _Pragma("unroll") for (int m = 2; m < 4; ++m)                              \
        _Pragma("unroll") for (int n = 0; n < 4; ++n)                          \
            acc[m][n] = MFMA(fah[m], fbh[n], acc[m][n]);                       \
    __builtin_amdgcn_s_setprio(0);                                             \
    __builtin_amdgcn_s_barrier();                                              \
    /* P2: read A-lo, stage B pair, advance ptrs */                            \
    _Pragma("unroll") for (int m = 0; m < 4; ++m)                              \
        fal[m] = *(const s8v*)(Lc + 8192 + (wm * 64 + m * 16 + lr) * 32 + kslot8); \
    if (DO_STAGE) { glds16(pBh, Ls + bw); glds16(pBl, Ls + bw + 4096);         \
        pAh0 += 32; pAh1 += 32; pAl0 += 32; pAl1 += 32; pBh += 32; pBl += 32; } \
    __builtin_amdgcn_s_barrier();                                              \
    __builtin_amdgcn_s_setprio(1);                                             \
    _Pragma("unroll") for (int m = 0; m < 4; ++m)                              \
        _Pragma("unroll") for (int n = 0; n < 4; ++n)                          \
            acc[m][n] = MFMA(fah[m], fbl[n], acc[m][n]);                       \
    __builtin_amdgcn_s_setprio(0);                                             \
    __builtin_amdgcn_s_barrier();                                              \
    /* P3: Al*Bh, tile-end wait */                                             \
    __builtin_amdgcn_s_setprio(1);                                             \
    _Pragma("unroll") for (int m = 0; m < 4; ++m)                              \
        _Pragma("unroll") for (int n = 0; n < 4; ++n)                          \
            acc[m][n] = MFMA(fal[m], fbh[n], acc[m][n]);                       \
    __builtin_amdgcn_s_setprio(0);                                             \
    if (VMODE == 0)      asm volatile("s_waitcnt vmcnt(6)" ::: "memory");      \
    else if (VMODE == 1) asm volatile("s_waitcnt vmcnt(0)" ::: "memory");      \
    if (VMODE != 2) __builtin_amdgcn_s_barrier();                              \
    __builtin_amdgcn_sched_barrier(0);                                         \
} while (0)

    // prologue: stage tiles 0 (buf0) and 1 (buf1)
    STAGE6(0);
    STAGE6(1);
    asm volatile("s_waitcnt vmcnt(6)" ::: "memory");   // tile-0 loads landed
    __builtin_amdgcn_s_barrier();
    __builtin_amdgcn_sched_barrier(0);

    // main loop: tiles 0..125 (42 x 3), tile t in buf t%3, staging t+2 into (t+2)%3
    for (int it = 0; it < 42; ++it) {
        KTILE(0, 2, 1, 0);
        KTILE(1, 0, 1, 0);
        KTILE(2, 1, 1, 0);
    }
    KTILE(0, 2, 0, 1);   // tile 126: drain tile-127 loads
    KTILE(1, 0, 0, 2);   // tile 127: nothing outstanding

#undef STAGE6
#undef KTILE

    // epilogue: relu, store fp32 H[b*4096+row][col]
    const int orow = n0 + wm * 64 + lk * 4;
    float* outp = Hout + ((size_t)b * 4096 + orow) * 256 + h0 + wn * 64 + lr;
#pragma unroll
    for (int m = 0; m < 4; ++m)
#pragma unroll
        for (int n = 0; n < 4; ++n)
#pragma unroll
            for (int q = 0; q < 4; ++q) {
                float v = acc[m][n][q];
                v = v > 0.f ? v : 0.f;
                outp[(size_t)(m * 16 + q) * 256 + n * 16] = v;
            }
}

// ---------------- final MLP: out[r] = relu(H[r,:] @ Wm1 + bm1) @ Wm2 + bm2 ----------------
__global__ __launch_bounds__(256) void mlp_k(
    const float* __restrict__ H, const float* __restrict__ Wm1,
    const float* __restrict__ bm1, const float* __restrict__ Wm2,
    const float* __restrict__ bm2, float* __restrict__ out)
{
    __shared__ float rb[4][256];
    const int w = threadIdx.x >> 6, lane = threadIdx.x & 63;
    const int gw0 = blockIdx.x * 4 + w;
    const int stride = gridDim.x * 4;
    for (int r = gw0; r < R_TOT; r += stride) {
        float4 v = *(const float4*)(H + (size_t)r * 256 + lane * 4);
        *(float4*)&rb[w][lane * 4] = v;
        __syncthreads();
        float acc = 0.f;
#pragma unroll 8
        for (int k = 0; k < 256; ++k)
            acc = fmaf(rb[w][k], Wm1[k * 64 + lane], acc);
        float m = acc + bm1[lane];
        m = m > 0.f ? m : 0.f;
        float s = m * Wm2[lane];
#pragma unroll
        for (int off = 32; off; off >>= 1) s += __shfl_down(s, off);
        if (lane == 0) out[r] = s + bm2[0];
        __syncthreads();
    }
}

// ---------------- launch ----------------
extern "C" void kernel_launch(void* const* d_in, const int* in_sizes, int n_in,
                              void* d_out, int out_size, void* d_ws, size_t ws_size,
                              hipStream_t stream) {
    (void)in_sizes; (void)n_in; (void)out_size; (void)ws_size;
    const float* X   = (const float*)d_in[0];
    const float* G   = (const float*)d_in[1];
    const float* W1  = (const float*)d_in[2];
    const float* b1  = (const float*)d_in[3];
    const float* W2  = (const float*)d_in[4];
    const float* b2  = (const float*)d_in[5];
    const float* Wm1 = (const float*)d_in[6];
    const float* bm1 = (const float*)d_in[7];
    const float* Wm2 = (const float*)d_in[8];
    const float* bm2 = (const float*)d_in[9];
    float* out = (float*)d_out;

    char* ws = (char*)d_ws;
    u16* Gh   = (u16*)(ws);                     // 33554432 B
    u16* Gl   = (u16*)(ws + 33554432u);         // 33554432 B
    u16* W1th = (u16*)(ws + 67108864u);         // 131072 B
    u16* W1tl = (u16*)(ws + 67239936u);
    u16* W2th = (u16*)(ws + 67371008u);
    u16* W2tl = (u16*)(ws + 67502080u);
    u16* Tth  = (u16*)(ws + 67633152u);         // 16777216 B
    u16* Ttl  = (u16*)(ws + 84410368u);         // 16777216 B
    float* Hb = (float*)(ws + 101187584u);      // 33554432 B  (total 134742016 B)

    splitK_k<<<2048, 256, 0, stream>>>(G, Gh, Gl, 16777216 / 4);
    splitT_k<<<256, 256, 0, stream>>>(W1, W1th, W1tl);
    splitT_k<<<256, 256, 0, stream>>>(W2, W2th, W2tl);

    // conv1 pre-prop: T1t = (X @ W1 + b1)^T, split
    gemm_small_k<<<dim3(2, 256), 256, 0, stream>>>(W1th, W1tl, X, b1, Tth, Ttl);
    // conv1 prop: H1 = relu(G @ T1)
    gemm_big_k<<<dim3(16, 2, 8), 512, 147456, stream>>>(Gh, Gl, Tth, Ttl, Hb);
    // conv2 pre-prop: T2t = (H1 @ W2 + b2)^T, split
    gemm_small_k<<<dim3(2, 256), 256, 0, stream>>>(W2th, W2tl, Hb, b2, Tth, Ttl);
    // conv2 prop: H2 = relu(G @ T2)
    gemm_big_k<<<dim3(16, 2, 8), 512, 147456, stream>>>(Gh, Gl, Tth, Ttl, Hb);
    // final MLP
    mlp_k<<<2048, 256, 0, stream>>>(Hb, Wm1, bm1, Wm2, bm2, out);
}